// Round 2
// baseline (4104.570 us; speedup 1.0000x reference)
//
#include <hip/hip_runtime.h>

#define BATCH 4
#define NPTS  2048
#define DIM   16
#define REGEPS 0.01f
#define DECAYF 0.9f
#define MINUPD 0.01f
#define MAXIT  50
#define LOGN   7.62461898616f   // ln(2048)

// ---- workspace layout (units of 4 bytes) ----
#define OFF_SX    0
#define OFF_SQ    (BATCH*NPTS*DIM)            // 131072
#define OFF_F     (OFF_SQ + BATCH*NPTS)       // 139264
#define OFF_G     (OFF_F + BATCH*NPTS)        // 147456
#define OFF_MEAN  (OFF_G + BATCH*NPTS)        // 155648
#define OFF_SCALE (OFF_MEAN + BATCH*DIM)      // 155712
#define OFF_EPS0  (OFF_SCALE + BATCH)         // 155716
#define OFF_UPD   (OFF_EPS0 + BATCH)          // 155720 (uint, atomicMax)
#define OFF_DONE  (OFF_UPD + BATCH)           // 155724 (int)
#define OFF_CNT   (OFF_DONE + BATCH)          // 155728 (64 ints)
// total ~623 KB

// ============================================================
// Preprocess: mean/std/scale per batch, sx=(x-mean)/scale, sq=|sx|^2,
// extent -> eps0, zero f/g/upd/done/counters.
// grid = BATCH blocks x 256 threads
// ============================================================
__global__ __launch_bounds__(256) void ot_preproc(const float* __restrict__ state,
                                                  float* __restrict__ ws) {
  const int b = blockIdx.x;
  const int tid = threadIdx.x;
  __shared__ float s_sum[16][17];
  __shared__ float s_sq[16][17];
  __shared__ float s_mean[16];
  __shared__ float s_red[8];
  __shared__ float s_scale_sh;

  const float* st = state + b * NPTS * DIM;
  const int d = tid & 15, grp = tid >> 4;
  float sm = 0.f, s2 = 0.f;
  for (int n = grp; n < NPTS; n += 16) {
    float x = st[n * DIM + d];
    sm += x; s2 += x * x;
  }
  s_sum[grp][d] = sm; s_sq[grp][d] = s2;
  __syncthreads();
  if (tid < 16) {
    float S = 0.f, Q = 0.f;
    for (int g2 = 0; g2 < 16; ++g2) { S += s_sum[g2][tid]; Q += s_sq[g2][tid]; }
    float mean = S * (1.0f / NPTS);
    float var  = fmaxf(Q * (1.0f / NPTS) - mean * mean, 0.f);
    float sd   = sqrtf(var);
    s_mean[tid] = mean;
    ws[OFF_MEAN + b * DIM + tid] = mean;
    s_sum[0][tid] = sd;   // reuse as std buffer
  }
  __syncthreads();
  if (tid == 0) {
    float dm = 0.f;
    for (int d2 = 0; d2 < 16; ++d2) dm = fmaxf(dm, s_sum[0][d2]);
    if (dm == 0.f) dm = 1.f;
    float scale = dm * 4.0f;          // * sqrt(D=16)
    s_scale_sh = scale;
    ws[OFF_SCALE + b] = scale;
  }
  __syncthreads();

  const float inv_scale = 1.0f / s_scale_sh;
  float vmin = 3.0e38f, vmax = -3.0e38f;
  float* sx = ws + OFF_SX + b * NPTS * DIM;
  float* sq = ws + OFF_SQ + b * NPTS;
  for (int n = tid; n < NPTS; n += 256) {
    const float4* rp = (const float4*)(st + n * DIM);
    float4 xs0 = rp[0], xs1 = rp[1], xs2 = rp[2], xs3 = rp[3];
    float xv[16] = {xs0.x,xs0.y,xs0.z,xs0.w, xs1.x,xs1.y,xs1.z,xs1.w,
                    xs2.x,xs2.y,xs2.z,xs2.w, xs3.x,xs3.y,xs3.z,xs3.w};
    float ov[16];
    float q = 0.f;
    #pragma unroll
    for (int e = 0; e < 16; ++e) {
      float v = (xv[e] - s_mean[e]) * inv_scale;
      ov[e] = v; q += v * v;
      vmin = fminf(vmin, v); vmax = fmaxf(vmax, v);
    }
    float4* op = (float4*)(sx + n * DIM);
    op[0] = make_float4(ov[0],ov[1],ov[2],ov[3]);
    op[1] = make_float4(ov[4],ov[5],ov[6],ov[7]);
    op[2] = make_float4(ov[8],ov[9],ov[10],ov[11]);
    op[3] = make_float4(ov[12],ov[13],ov[14],ov[15]);
    sq[n] = q;
  }
  // zero f/g
  float* fv = ws + OFF_F + b * NPTS;
  float* gv = ws + OFF_G + b * NPTS;
  for (int n = tid; n < NPTS; n += 256) { fv[n] = 0.f; gv[n] = 0.f; }
  // block min/max reduce for extent
  #pragma unroll
  for (int off = 32; off > 0; off >>= 1) {
    vmin = fminf(vmin, __shfl_xor(vmin, off));
    vmax = fmaxf(vmax, __shfl_xor(vmax, off));
  }
  const int wv = tid >> 6, ln = tid & 63;
  if (ln == 0) { s_red[wv] = vmin; s_red[4 + wv] = vmax; }
  __syncthreads();
  if (tid == 0) {
    float mn = fminf(fminf(s_red[0], s_red[1]), fminf(s_red[2], s_red[3]));
    float mx = fmaxf(fmaxf(s_red[4], s_red[5]), fmaxf(s_red[6], s_red[7]));
    ws[OFF_EPS0 + b] = mx - mn;
    ((unsigned int*)ws)[OFF_UPD + b] = 0u;
    ((int*)ws)[OFF_DONE + b] = 0;
  }
  if (b == 0 && tid < 64) ((int*)ws)[OFF_CNT + tid] = 0;
}

// ============================================================
// One Sinkhorn half-step (isF=1: f-update, isF=0: g-update + bookkeeping).
// grid = BATCH * (NPTS/16) = 512 blocks x 256 threads.
// Each wave owns 4 rows; each lane handles 4 consecutive js per 256-tile.
// ============================================================
__global__ __launch_bounds__(256) void ot_pass(float* __restrict__ ws,
                                               const float* __restrict__ wlog,
                                               int it, int isF) {
  __shared__ float s_xt[DIM][256];   // transposed sx tile [d][j]
  __shared__ float s_a[256];
  __shared__ float s_q[256];

  const int bid = blockIdx.x;
  const int b  = bid >> 7;     // 128 row-blocks / batch
  const int rb = bid & 127;
  const int tid = threadIdx.x;
  const int w = tid >> 6, l = tid & 63;

  if (!((const int*)ws)[OFF_DONE + b]) {
    float e = ws[OFF_EPS0 + b];
    #pragma unroll 1
    for (int t = 0; t < it; ++t) e = fmaxf(e * DECAYF, REGEPS);
    const float inv_e = 1.0f / e;

    const float* __restrict__ sx = ws + OFF_SX + b * NPTS * DIM;
    const float* __restrict__ sq = ws + OFF_SQ + b * NPTS;
    float* fv = ws + OFF_F + b * NPTS;
    float* gv = ws + OFF_G + b * NPTS;
    const float* __restrict__ wl = wlog + b * NPTS;

    const int row0 = rb * 16 + w * 4;
    float sxi[4][DIM], ci[4], m[4], ssum[4];
    #pragma unroll
    for (int r = 0; r < 4; ++r) {
      const int i = row0 + r;
      ci[r] = sq[i];
      const float4* rp = (const float4*)(sx + i * DIM);
      #pragma unroll
      for (int c4 = 0; c4 < 4; ++c4) {
        float4 t = rp[c4];
        sxi[r][c4*4+0] = -2.0f * t.x; sxi[r][c4*4+1] = -2.0f * t.y;
        sxi[r][c4*4+2] = -2.0f * t.z; sxi[r][c4*4+3] = -2.0f * t.w;
      }
      m[r] = -3.0e38f; ssum[r] = 0.0f;
    }

    const float* __restrict__ src = isF ? gv : fv;
    for (int k = 0; k < NPTS / 256; ++k) {
      __syncthreads();
      { // stage tile: thread tid handles j = k*256+tid
        const int j = k * 256 + tid;
        const float4* rp = (const float4*)(sx + j * DIM);
        float4 t0 = rp[0], t1 = rp[1], t2 = rp[2], t3 = rp[3];
        s_xt[0][tid]=t0.x;  s_xt[1][tid]=t0.y;  s_xt[2][tid]=t0.z;  s_xt[3][tid]=t0.w;
        s_xt[4][tid]=t1.x;  s_xt[5][tid]=t1.y;  s_xt[6][tid]=t1.z;  s_xt[7][tid]=t1.w;
        s_xt[8][tid]=t2.x;  s_xt[9][tid]=t2.y;  s_xt[10][tid]=t2.z; s_xt[11][tid]=t2.w;
        s_xt[12][tid]=t3.x; s_xt[13][tid]=t3.y; s_xt[14][tid]=t3.z; s_xt[15][tid]=t3.w;
        s_q[tid] = sq[j];
        float aj = src[j] * inv_e;
        if (!isF) aj += wl[j];
        s_a[tid] = aj;
      }
      __syncthreads();
      const float4 av = *(const float4*)&s_a[4 * l];
      const float4 qv = *(const float4*)&s_q[4 * l];
      float acc[4][4];
      #pragma unroll
      for (int r = 0; r < 4; ++r) {
        acc[r][0] = ci[r] + qv.x; acc[r][1] = ci[r] + qv.y;
        acc[r][2] = ci[r] + qv.z; acc[r][3] = ci[r] + qv.w;
      }
      #pragma unroll
      for (int dd = 0; dd < DIM; ++dd) {
        const float4 xj = *(const float4*)&s_xt[dd][4 * l];
        #pragma unroll
        for (int r = 0; r < 4; ++r) {
          const float xr = sxi[r][dd];
          acc[r][0] = fmaf(xr, xj.x, acc[r][0]);
          acc[r][1] = fmaf(xr, xj.y, acc[r][1]);
          acc[r][2] = fmaf(xr, xj.z, acc[r][2]);
          acc[r][3] = fmaf(xr, xj.w, acc[r][3]);
        }
      }
      #pragma unroll
      for (int r = 0; r < 4; ++r) {
        float v0 = fmaf(fmaxf(acc[r][0], 0.0f), -inv_e, av.x);
        float v1 = fmaf(fmaxf(acc[r][1], 0.0f), -inv_e, av.y);
        float v2 = fmaf(fmaxf(acc[r][2], 0.0f), -inv_e, av.z);
        float v3 = fmaf(fmaxf(acc[r][3], 0.0f), -inv_e, av.w);
        float cmx = fmaxf(fmaxf(v0, v1), fmaxf(v2, v3));
        float nm = fmaxf(m[r], cmx);
        float e0 = __expf(m[r] - nm);
        float sadd = __expf(v0-nm) + __expf(v1-nm) + __expf(v2-nm) + __expf(v3-nm);
        ssum[r] = fmaf(ssum[r], e0, sadd);
        m[r] = nm;
      }
    }
    // wave butterfly combine of (m, ssum)
    #pragma unroll
    for (int off = 1; off < 64; off <<= 1) {
      #pragma unroll
      for (int r = 0; r < 4; ++r) {
        float om = __shfl_xor(m[r], off);
        float os = __shfl_xor(ssum[r], off);
        float nm = fmaxf(m[r], om);
        ssum[r] = fmaf(ssum[r], __expf(m[r]-nm), os * __expf(om-nm));
        m[r] = nm;
      }
    }
    if (l < 4) {
      const int r = l;
      float L = m[r] + __logf(ssum[r]);
      if (isF) L -= LOGN;
      const float nv = -e * L;
      float* dst = isF ? fv : gv;
      const int i = row0 + r;
      const float old = dst[i];
      dst[i] = nv;
      atomicMax((unsigned int*)ws + OFF_UPD + b, __float_as_uint(fabsf(nv - old)));
    }
  }

  // per-iteration bookkeeping fused into the g-pass (last block updates done)
  if (!isF) {
    __syncthreads();
    if (tid == 0) {
      __threadfence();
      const int old = atomicAdd((int*)ws + OFF_CNT + it, 1);
      if (old == (int)gridDim.x - 1) {
        __threadfence();
        #pragma unroll 1
        for (int bb = 0; bb < BATCH; ++bb) {
          if (!((int*)ws)[OFF_DONE + bb]) {
            // device-scope read of upd via atomic
            float u = __uint_as_float(atomicMax((unsigned int*)ws + OFF_UPD + bb, 0u));
            float e2 = ws[OFF_EPS0 + bb];
            #pragma unroll 1
            for (int t = 0; t < it; ++t) e2 = fmaxf(e2 * DECAYF, REGEPS);
            if (u < MINUPD && e2 <= REGEPS) ((int*)ws)[OFF_DONE + bb] = 1;
          }
          ((unsigned int*)ws)[OFF_UPD + bb] = 0u;
        }
        __threadfence();
      }
    }
  }
}

// ============================================================
// Output: new_state[b,m,d] = N * sum_n exp(logT[n,m]) * state[n,d]
//       = N * (scale * sum_n T*sx[n,d] + mean[d] * sum_n T)
// grid = BATCH * (NPTS/8) = 1024 blocks x 256 threads; 2 rows / wave.
// Also fills uniform_log_w.
// ============================================================
__global__ __launch_bounds__(256) void ot_out(float* __restrict__ ws,
                                              const float* __restrict__ wlog,
                                              float* __restrict__ out) {
  __shared__ float s_xt[DIM][256];
  __shared__ float s_p[256];
  __shared__ float s_q[256];
  const int bid = blockIdx.x;
  const int b  = bid >> 8;     // 256 row-blocks / batch
  const int rb = bid & 255;
  const int tid = threadIdx.x;
  const int w = tid >> 6, l = tid & 63;
  const float invR = 1.0f / REGEPS;

  const float* __restrict__ sx = ws + OFF_SX + b * NPTS * DIM;
  const float* __restrict__ sq = ws + OFF_SQ + b * NPTS;
  const float* __restrict__ fv = ws + OFF_F + b * NPTS;
  const float* __restrict__ gv = ws + OFF_G + b * NPTS;
  const float* __restrict__ wl = wlog + b * NPTS;

  const int row0 = rb * 8 + w * 2;
  float sxm[2][DIM], cm2[2], qm[2], acc[2][DIM], accT[2];
  #pragma unroll
  for (int r = 0; r < 2; ++r) {
    const int mrow = row0 + r;
    cm2[r] = sq[mrow];
    qm[r]  = gv[mrow] * invR;
    const float4* rp = (const float4*)(sx + mrow * DIM);
    #pragma unroll
    for (int c4 = 0; c4 < 4; ++c4) {
      float4 t = rp[c4];
      sxm[r][c4*4+0] = -2.0f * t.x; sxm[r][c4*4+1] = -2.0f * t.y;
      sxm[r][c4*4+2] = -2.0f * t.z; sxm[r][c4*4+3] = -2.0f * t.w;
    }
    #pragma unroll
    for (int dd = 0; dd < DIM; ++dd) acc[r][dd] = 0.0f;
    accT[r] = 0.0f;
  }

  for (int k = 0; k < NPTS / 256; ++k) {
    __syncthreads();
    {
      const int n = k * 256 + tid;
      const float4* rp = (const float4*)(sx + n * DIM);
      float4 t0 = rp[0], t1 = rp[1], t2 = rp[2], t3 = rp[3];
      s_xt[0][tid]=t0.x;  s_xt[1][tid]=t0.y;  s_xt[2][tid]=t0.z;  s_xt[3][tid]=t0.w;
      s_xt[4][tid]=t1.x;  s_xt[5][tid]=t1.y;  s_xt[6][tid]=t1.z;  s_xt[7][tid]=t1.w;
      s_xt[8][tid]=t2.x;  s_xt[9][tid]=t2.y;  s_xt[10][tid]=t2.z; s_xt[11][tid]=t2.w;
      s_xt[12][tid]=t3.x; s_xt[13][tid]=t3.y; s_xt[14][tid]=t3.z; s_xt[15][tid]=t3.w;
      s_q[tid] = sq[n];
      s_p[tid] = wl[n] - LOGN + fv[n] * invR;
    }
    __syncthreads();
    const float4 pv = *(const float4*)&s_p[4 * l];
    const float4 qv = *(const float4*)&s_q[4 * l];
    float a2[2][4];
    #pragma unroll
    for (int r = 0; r < 2; ++r) {
      a2[r][0] = cm2[r] + qv.x; a2[r][1] = cm2[r] + qv.y;
      a2[r][2] = cm2[r] + qv.z; a2[r][3] = cm2[r] + qv.w;
    }
    #pragma unroll
    for (int dd = 0; dd < DIM; ++dd) {
      const float4 xj = *(const float4*)&s_xt[dd][4 * l];
      #pragma unroll
      for (int r = 0; r < 2; ++r) {
        const float xr = sxm[r][dd];
        a2[r][0] = fmaf(xr, xj.x, a2[r][0]);
        a2[r][1] = fmaf(xr, xj.y, a2[r][1]);
        a2[r][2] = fmaf(xr, xj.z, a2[r][2]);
        a2[r][3] = fmaf(xr, xj.w, a2[r][3]);
      }
    }
    float T[2][4];
    #pragma unroll
    for (int r = 0; r < 2; ++r) {
      T[r][0] = __expf(fmaf(fmaxf(a2[r][0], 0.f), -invR, pv.x + qm[r]));
      T[r][1] = __expf(fmaf(fmaxf(a2[r][1], 0.f), -invR, pv.y + qm[r]));
      T[r][2] = __expf(fmaf(fmaxf(a2[r][2], 0.f), -invR, pv.z + qm[r]));
      T[r][3] = __expf(fmaf(fmaxf(a2[r][3], 0.f), -invR, pv.w + qm[r]));
      accT[r] += (T[r][0] + T[r][1]) + (T[r][2] + T[r][3]);
    }
    #pragma unroll
    for (int dd = 0; dd < DIM; ++dd) {
      const float4 xj = *(const float4*)&s_xt[dd][4 * l];
      #pragma unroll
      for (int r = 0; r < 2; ++r) {
        float t = acc[r][dd];
        t = fmaf(T[r][0], xj.x, t);
        t = fmaf(T[r][1], xj.y, t);
        t = fmaf(T[r][2], xj.z, t);
        t = fmaf(T[r][3], xj.w, t);
        acc[r][dd] = t;
      }
    }
  }
  // butterfly sum across wave
  #pragma unroll
  for (int off = 1; off < 64; off <<= 1) {
    #pragma unroll
    for (int r = 0; r < 2; ++r) {
      #pragma unroll
      for (int dd = 0; dd < DIM; ++dd) acc[r][dd] += __shfl_xor(acc[r][dd], off);
      accT[r] += __shfl_xor(accT[r], off);
    }
  }
  if (l == 0) {
    const float scale = ws[OFF_SCALE + b];
    const float* mean = ws + OFF_MEAN + b * DIM;
    #pragma unroll
    for (int r = 0; r < 2; ++r) {
      const int mrow = row0 + r;
      float ov[16];
      #pragma unroll
      for (int dd = 0; dd < DIM; ++dd)
        ov[dd] = (float)NPTS * fmaf(scale, acc[r][dd], mean[dd] * accT[r]);
      float4* op = (float4*)(out + (b * NPTS + mrow) * DIM);
      op[0] = make_float4(ov[0],ov[1],ov[2],ov[3]);
      op[1] = make_float4(ov[4],ov[5],ov[6],ov[7]);
      op[2] = make_float4(ov[8],ov[9],ov[10],ov[11]);
      op[3] = make_float4(ov[12],ov[13],ov[14],ov[15]);
    }
  }
  if (tid < 8) out[BATCH * NPTS * DIM + b * NPTS + rb * 8 + tid] = -LOGN;
}

extern "C" void kernel_launch(void* const* d_in, const int* in_sizes, int n_in,
                              void* d_out, int out_size, void* d_ws, size_t ws_size,
                              hipStream_t stream) {
  (void)in_sizes; (void)n_in; (void)out_size; (void)ws_size;
  const float* state  = (const float*)d_in[0];
  const float* weight = (const float*)d_in[1];
  float* out = (float*)d_out;
  float* ws  = (float*)d_ws;

  ot_preproc<<<dim3(BATCH), dim3(256), 0, stream>>>(state, ws);
  for (int it = 0; it < MAXIT; ++it) {
    ot_pass<<<dim3(BATCH * NPTS / 16), dim3(256), 0, stream>>>(ws, weight, it, 1);
    ot_pass<<<dim3(BATCH * NPTS / 16), dim3(256), 0, stream>>>(ws, weight, it, 0);
  }
  ot_out<<<dim3(BATCH * NPTS / 8), dim3(256), 0, stream>>>(ws, weight, out);
}